// Round 4
// baseline (229.904 us; speedup 1.0000x reference)
//
#include <hip/hip_runtime.h>
#include <hip/hip_bf16.h>
#include <cstddef>

#define TT 50
#define NN 512
#define DIN 3
#define HH 128
#define NHD 4
#define NPG 64

typedef short short8 __attribute__((ext_vector_type(8)));
typedef float f32x4 __attribute__((ext_vector_type(4)));

// ---- fused attention LDS layout (ushort elems) ----
#define SROW 136
#define VROW 56
#define PROW 72
#define SQ_OFF 0
#define SK_OFF 6800
#define SV_OFF 13600
#define PQ_OFF 20784
#define SMEM_ELEMS 39216      // 78,432 B -> 2 blocks/CU

static __device__ __forceinline__ unsigned short f2b(float f) {
    unsigned int u = __builtin_bit_cast(unsigned int, f);
    unsigned int r = (u + 0x7fffu + ((u >> 16) & 1u)) >> 16;
    return (unsigned short)r;
}

// Barrier that does NOT drain vmcnt: LDS visibility via lgkmcnt(0), raw
// s_barrier, sched_barrier fences to stop the scheduler moving LDS ops
// across. Prefetched global loads stay in flight across stage boundaries.
static __device__ __forceinline__ void block_sync() {
    __builtin_amdgcn_sched_barrier(0);
    asm volatile("s_waitcnt lgkmcnt(0)");
    __builtin_amdgcn_s_barrier();
    __builtin_amdgcn_sched_barrier(0);
}

// ---------------------------------------------------------------------------
// Kernel A0: ego mask -> MF [T][NN]
// ---------------------------------------------------------------------------
__global__ __launch_bounds__(256) void mf_kernel(
    const int* __restrict__ ego, float* __restrict__ MF)
{
    const int idx = blockIdx.x * 256 + threadIdx.x;   // < T*NN
    const int t = idx >> 9;
    const int i = idx & 511;
    const int b = i >> 6, p = i & 63;
    MF[idx] = (ego[b * (TT * NPG) + t * NPG + p] != 0) ? 1.0f : 0.0f;
}

// ---------------------------------------------------------------------------
// Kernel A2: edge extraction. block = (t, 32-row chunk), 256 threads process
// 2 rows at a time (128 threads/row, float4 each). Mask staged once/block.
// ---------------------------------------------------------------------------
__global__ __launch_bounds__(256) void edge_kernel(
    const float* __restrict__ adj, const float* __restrict__ MF,
    int* __restrict__ CNT, unsigned short* __restrict__ IDX)
{
    const int bid = blockIdx.x;        // t*16 + chunk
    const int t = bid >> 4;
    const int r0 = (bid & 15) * 32;
    const int tid = threadIdx.x;

    __shared__ float mfS[NN];
    for (int j = tid; j < NN; j += 256) mfS[j] = MF[t * NN + j];
    __syncthreads();

    const int half = tid >> 7;
    const int l = tid & 127;

    for (int rr = 0; rr < 32; rr += 2) {
        const int i = r0 + rr + half;
        if (mfS[i] == 0.0f) continue;   // uniform per half-block
        const float4 a4 = *reinterpret_cast<const float4*>(
            &adj[(size_t)t * NN * NN + (size_t)i * NN + l * 4]);
        const float av[4] = {a4.x, a4.y, a4.z, a4.w};
        const int jbase = l * 4;
#pragma unroll
        for (int u = 0; u < 4; ++u) {
            const int j = jbase + u;
            if (av[u] != 0.0f && mfS[j] != 0.0f) {
                int pos = atomicAdd(&CNT[t * NN + j], 1);
                IDX[((size_t)t * NN + j) * NN + pos] = (unsigned short)i;
            }
        }
    }
}

// ---------------------------------------------------------------------------
// Kernel A3: DINV = mf ? rsqrt(cnt+1) : 0
// ---------------------------------------------------------------------------
__global__ __launch_bounds__(256) void dinv_kernel(
    const float* __restrict__ MF, const int* __restrict__ CNT,
    float* __restrict__ DINV)
{
    const int idx = blockIdx.x * 256 + threadIdx.x;
    DINV[idx] = (MF[idx] != 0.0f) ? rsqrtf((float)CNT[idx] + 1.0f) : 0.0f;
}

// ---------------------------------------------------------------------------
// Kernel B: XW1 = (x @ W1) * dinv
// ---------------------------------------------------------------------------
__global__ __launch_bounds__(256) void xw1_kernel(
    const float* __restrict__ x, const float* __restrict__ W1,
    const float* __restrict__ DINV, float* __restrict__ XW)
{
    const int idx = blockIdx.x * 256 + threadIdx.x;
    const int t = idx >> 16;
    const int r = idx & 65535;
    const int i = r >> 7;
    const int f = r & 127;
    const float* xp = x + ((size_t)t * NN + i) * DIN;
    float v = xp[0] * W1[f] + xp[1] * W1[HH + f] + xp[2] * W1[2 * HH + f];
    XW[idx] = v * DINV[t * NN + i];
}

// ---------------------------------------------------------------------------
// Kernel C: column aggregation via neighbor lists + bias (+ReLU)
// ---------------------------------------------------------------------------
__global__ __launch_bounds__(128) void agg_kernel(
    const float* __restrict__ XW, const float* __restrict__ MF,
    const float* __restrict__ DINV, const int* __restrict__ CNT,
    const unsigned short* __restrict__ IDX, const float* __restrict__ bias,
    float* __restrict__ OUT, int do_relu)
{
    const int bid = blockIdx.x;
    const int t = bid / NN;
    const int j = bid - t * NN;
    const int f = threadIdx.x;

    __shared__ unsigned short sidx[NN];

    const float mfj = MF[t * NN + j];
    int cnt = 0;
    if (mfj != 0.0f) cnt = CNT[t * NN + j];
    const unsigned short* lst = IDX + ((size_t)t * NN + j) * NN;
    for (int k = f; k < cnt; k += 128) sidx[k] = lst[k];
    __syncthreads();

    float outv = 0.0f;
    if (mfj != 0.0f) {
        const float* base = XW + (size_t)t * NN * HH;
        float acc = base[j * HH + f];
        for (int k = 0; k < cnt; ++k) {
            acc += base[(int)sidx[k] * HH + f];
        }
        outv = DINV[t * NN + j] * acc + bias[f];
        if (do_relu) outv = fmaxf(outv, 0.0f);
    }
    OUT[(size_t)t * NN * HH + j * HH + f] = outv;
}

// ---------------------------------------------------------------------------
// Kernel D: XW2 = (H1 @ W2) * dinv, W2 staged in LDS
// ---------------------------------------------------------------------------
__global__ __launch_bounds__(128) void xw2_kernel(
    const float* __restrict__ Hin, const float* __restrict__ W2,
    const float* __restrict__ DINV, float* __restrict__ XW2)
{
    const int bid = blockIdx.x;
    const int t = bid >> 4;
    const int chunk = bid & 15;
    const int f = threadIdx.x;

    __shared__ float W2S[HH * HH];
    __shared__ float rowsS[32 * HH];

    for (int idx = f; idx < HH * HH; idx += 128) W2S[idx] = W2[idx];
    const float* hb = Hin + (size_t)t * NN * HH + (size_t)chunk * 32 * HH;
    for (int idx = f; idx < 32 * HH; idx += 128) rowsS[idx] = hb[idx];
    __syncthreads();

    float acc[32];
#pragma unroll
    for (int r = 0; r < 32; ++r) acc[r] = 0.0f;

    for (int h = 0; h < HH; ++h) {
        float w = W2S[h * HH + f];
#pragma unroll
        for (int r = 0; r < 32; ++r) acc[r] = fmaf(rowsS[r * HH + h], w, acc[r]);
    }

    float* ob = XW2 + (size_t)t * NN * HH + (size_t)chunk * 32 * HH;
    const float* dv = DINV + t * NN + chunk * 32;
#pragma unroll
    for (int r = 0; r < 32; ++r) ob[r * HH + f] = acc[r] * dv[r];
}

// ---------------------------------------------------------------------------
// Kernel E (MFMA, software-pipelined weights)
// ---------------------------------------------------------------------------
__device__ __forceinline__ void issue_wload(const float* __restrict__ W,
                                            int nt0, int c, int g,
                                            float4 (&wr)[16])
{
#pragma unroll
    for (int i = 0; i < 2; ++i) {
        const float* base = W + (16 * (nt0 + i) + c) * HH + 8 * g;
#pragma unroll
        for (int kb = 0; kb < 4; ++kb) {
            wr[i * 8 + kb * 2]     = *reinterpret_cast<const float4*>(base + kb * 32);
            wr[i * 8 + kb * 2 + 1] = *reinterpret_cast<const float4*>(base + kb * 32 + 4);
        }
    }
}

// MODE: 0 = LDS store (SROW); 1 = +scale; 2 = transposed store (VROW);
//       3 = fp32 global store. PF: prefetch Wnext into wr after conversion.
template<int MODE, bool PF>
__device__ __forceinline__ void stage_pf(
    unsigned short* __restrict__ sm, int in_off, int out_off,
    float4 (&wr)[16], const float* __restrict__ Wnext,
    const float* __restrict__ bias, float* __restrict__ gout)
{
    const int tid = threadIdx.x;
    const int lane = tid & 63;
    const int wid = tid >> 6;
    const int g = lane >> 4, c = lane & 15;
    const int nt0 = 2 * wid;

    const float bv0 = bias[16 * nt0 + c];
    const float bv1 = bias[16 * nt0 + 16 + c];

    // convert landed weights (waits on this stage's loads)
    short8 bf[2][4];
#pragma unroll
    for (int i = 0; i < 2; ++i)
#pragma unroll
        for (int kb = 0; kb < 4; ++kb) {
            float4 w0 = wr[i * 8 + kb * 2];
            float4 w1 = wr[i * 8 + kb * 2 + 1];
            short8 tt;
            tt[0] = (short)f2b(w0.x); tt[1] = (short)f2b(w0.y);
            tt[2] = (short)f2b(w0.z); tt[3] = (short)f2b(w0.w);
            tt[4] = (short)f2b(w1.x); tt[5] = (short)f2b(w1.y);
            tt[6] = (short)f2b(w1.z); tt[7] = (short)f2b(w1.w);
            bf[i][kb] = tt;
        }
    // immediately issue next stage's loads into the freed registers
    if (PF) issue_wload(Wnext, nt0, c, g, wr);

    f32x4 acc[4][2];
#pragma unroll
    for (int m = 0; m < 4; ++m)
#pragma unroll
        for (int i = 0; i < 2; ++i)
            acc[m][i] = (f32x4)(0.0f);

#pragma unroll
    for (int kb = 0; kb < 4; ++kb) {
        short8 af[4];
#pragma unroll
        for (int m = 0; m < 4; ++m)
            af[m] = *reinterpret_cast<const short8*>(&sm[in_off + (16 * m + c) * SROW + kb * 32 + 8 * g]);
#pragma unroll
        for (int m = 0; m < 4; ++m)
#pragma unroll
            for (int i = 0; i < 2; ++i)
                acc[m][i] = __builtin_amdgcn_mfma_f32_16x16x32_bf16(af[m], bf[i][kb], acc[m][i], 0, 0, 0);
    }
    block_sync();   // all reads of in_off done (in-place safe)

    constexpr float scale = 0.17677669529663687f;  // 1/sqrt(32)
#pragma unroll
    for (int m = 0; m < 4; ++m)
#pragma unroll
        for (int i = 0; i < 2; ++i)
#pragma unroll
            for (int r = 0; r < 4; ++r) {
                const int row = 16 * m + 4 * g + r;
                if (row >= TT) continue;
                float v = acc[m][i][r] + (i ? bv1 : bv0);
                if (MODE == 1) v *= scale;
                const int col = 16 * (nt0 + i) + c;
                if (MODE == 3)      gout[row * HH + col] = v;
                else if (MODE == 2) sm[out_off + col * VROW + row] = f2b(v);
                else                sm[out_off + row * SROW + col] = f2b(v);
            }
    block_sync();
}

__global__ __launch_bounds__(256, 2) void node_attn_kernel(
    const float* __restrict__ EMB,
    const float* __restrict__ Wq, const float* __restrict__ bq,
    const float* __restrict__ Wk, const float* __restrict__ bk,
    const float* __restrict__ Wv, const float* __restrict__ bv,
    const float* __restrict__ W_in, const float* __restrict__ b_in,
    const float* __restrict__ W_out, const float* __restrict__ b_out,
    float* __restrict__ out)
{
    __shared__ unsigned short sm[SMEM_ELEMS];
    const int n = blockIdx.x;
    const int tid = threadIdx.x;
    const int lane = tid & 63;
    const int wid = tid >> 6;
    const int g = lane >> 4, c = lane & 15;
    const int nt0 = 2 * wid;

    const size_t nHH = (size_t)n * HH * HH;
    const size_t n3HH = (size_t)n * 3 * HH * HH;

    // issue stage-0 weight loads first — overlap with emb staging
    float4 wr[16];
    issue_wload(Wq + nHH, nt0, c, g, wr);

    for (int idx = tid; idx < HH * 6 + 16; idx += 256) {
        if (idx < HH * 6) {
            int d = idx / 6, cc = idx - d * 6;
            sm[SV_OFF + d * VROW + TT + cc] = 0;
        } else {
            sm[SV_OFF + HH * VROW + (idx - HH * 6)] = 0;
        }
    }
    for (int idx = tid; idx < TT * (HH / 4); idx += 256) {
        int t = idx >> 5;
        int h4 = (idx & 31) * 4;
        float4 v = *reinterpret_cast<const float4*>(&EMB[((size_t)t * NN + n) * HH + h4]);
        unsigned short* p = &sm[PQ_OFF + t * SROW + h4];
        p[0] = f2b(v.x); p[1] = f2b(v.y); p[2] = f2b(v.z); p[3] = f2b(v.w);
    }
    block_sync();

    stage_pf<0, true>(sm, PQ_OFF, SQ_OFF, wr, Wk + nHH,              bq + (size_t)n * HH,              nullptr);
    stage_pf<0, true>(sm, PQ_OFF, SK_OFF, wr, Wv + nHH,              bk + (size_t)n * HH,              nullptr);
    stage_pf<0, true>(sm, PQ_OFF, SV_OFF, wr, W_in + n3HH,           bv + (size_t)n * HH,              nullptr);
    stage_pf<1, true>(sm, SQ_OFF, SQ_OFF, wr, W_in + n3HH + HH * HH, b_in + (size_t)n * 3 * HH,        nullptr);
    stage_pf<0, true>(sm, SK_OFF, SK_OFF, wr, W_in + n3HH + 2 * HH * HH, b_in + (size_t)n * 3 * HH + HH, nullptr);
    stage_pf<2, true>(sm, SV_OFF, SV_OFF, wr, W_out + nHH,           b_in + (size_t)n * 3 * HH + 2 * HH, nullptr);
    // wr now holds W_out loads in flight across the whole attention section

    const int hd = wid;

    f32x4 sacc[4][4];
#pragma unroll
    for (int m = 0; m < 4; ++m)
#pragma unroll
        for (int j = 0; j < 4; ++j) sacc[m][j] = (f32x4)(0.0f);

    short8 aq[4], bk8[4];
#pragma unroll
    for (int m = 0; m < 4; ++m)
        aq[m] = *reinterpret_cast<const short8*>(&sm[SQ_OFF + (16 * m + c) * SROW + hd * 32 + 8 * g]);
#pragma unroll
    for (int j = 0; j < 4; ++j)
        bk8[j] = *reinterpret_cast<const short8*>(&sm[SK_OFF + (16 * j + c) * SROW + hd * 32 + 8 * g]);
#pragma unroll
    for (int m = 0; m < 4; ++m)
#pragma unroll
        for (int j = 0; j < 4; ++j)
            sacc[m][j] = __builtin_amdgcn_mfma_f32_16x16x32_bf16(aq[m], bk8[j], sacc[m][j], 0, 0, 0);

    const bool mask3 = (c >= 2);
    unsigned short* Pbase = &sm[PQ_OFF + hd * 64 * PROW];
#pragma unroll
    for (int m = 0; m < 4; ++m)
#pragma unroll
        for (int r = 0; r < 4; ++r) {
            float v0 = sacc[m][0][r], v1 = sacc[m][1][r], v2 = sacc[m][2][r];
            float v3 = mask3 ? -3.0e38f : sacc[m][3][r];
            float mx = fmaxf(fmaxf(v0, v1), fmaxf(v2, v3));
            mx = fmaxf(mx, __shfl_xor(mx, 1, 16));
            mx = fmaxf(mx, __shfl_xor(mx, 2, 16));
            mx = fmaxf(mx, __shfl_xor(mx, 4, 16));
            mx = fmaxf(mx, __shfl_xor(mx, 8, 16));
            float e0 = __expf(v0 - mx), e1 = __expf(v1 - mx), e2 = __expf(v2 - mx);
            float e3 = mask3 ? 0.0f : __expf(v3 - mx);
            float sum_ = e0 + e1 + e2 + e3;
            sum_ += __shfl_xor(sum_, 1, 16);
            sum_ += __shfl_xor(sum_, 2, 16);
            sum_ += __shfl_xor(sum_, 4, 16);
            sum_ += __shfl_xor(sum_, 8, 16);
            float inv = 1.0f / sum_;
            const int q = 16 * m + 4 * g + r;
            unsigned short* pr = Pbase + q * PROW;
            pr[c]      = f2b(e0 * inv);
            pr[16 + c] = f2b(e1 * inv);
            pr[32 + c] = f2b(e2 * inv);
            pr[48 + c] = f2b(e3 * inv);
        }
    block_sync();

    f32x4 pacc[2][4];
#pragma unroll
    for (int mtd = 0; mtd < 2; ++mtd)
#pragma unroll
        for (int ntq = 0; ntq < 4; ++ntq) pacc[mtd][ntq] = (f32x4)(0.0f);

#pragma unroll
    for (int kb = 0; kb < 2; ++kb) {
        short8 av[2], bp[4];
#pragma unroll
        for (int mtd = 0; mtd < 2; ++mtd)
            av[mtd] = *reinterpret_cast<const short8*>(&sm[SV_OFF + (hd * 32 + 16 * mtd + c) * VROW + kb * 32 + 8 * g]);
#pragma unroll
        for (int ntq = 0; ntq < 4; ++ntq)
            bp[ntq] = *reinterpret_cast<const short8*>(&sm[PQ_OFF + hd * 64 * PROW + (16 * ntq + c) * PROW + kb * 32 + 8 * g]);
#pragma unroll
        for (int mtd = 0; mtd < 2; ++mtd)
#pragma unroll
            for (int ntq = 0; ntq < 4; ++ntq)
                pacc[mtd][ntq] = __builtin_amdgcn_mfma_f32_16x16x32_bf16(av[mtd], bp[ntq], pacc[mtd][ntq], 0, 0, 0);
    }

#pragma unroll
    for (int mtd = 0; mtd < 2; ++mtd)
#pragma unroll
        for (int ntq = 0; ntq < 4; ++ntq)
#pragma unroll
            for (int r = 0; r < 4; ++r) {
                const int q = 16 * ntq + c;
                if (q < TT)
                    sm[SQ_OFF + q * SROW + hd * 32 + 16 * mtd + 4 * g + r] = f2b(pacc[mtd][ntq][r]);
            }
    block_sync();

    stage_pf<3, false>(sm, SQ_OFF, 0, wr, nullptr, b_out + (size_t)n * HH, out + (size_t)n * TT * HH);
}

// ---------------------------------------------------------------------------
extern "C" void kernel_launch(void* const* d_in, const int* in_sizes, int n_in,
                              void* d_out, int out_size, void* d_ws, size_t ws_size,
                              hipStream_t stream)
{
    const float* x     = (const float*)d_in[0];
    const float* adj   = (const float*)d_in[1];
    const int*   ego   = (const int*)d_in[2];
    const float* W1    = (const float*)d_in[3];
    const float* b1    = (const float*)d_in[4];
    const float* W2    = (const float*)d_in[5];
    const float* b2    = (const float*)d_in[6];
    const float* Wq    = (const float*)d_in[7];
    const float* bq    = (const float*)d_in[8];
    const float* Wk    = (const float*)d_in[9];
    const float* bk    = (const float*)d_in[10];
    const float* Wv    = (const float*)d_in[11];
    const float* bv    = (const float*)d_in[12];
    const float* W_in  = (const float*)d_in[13];
    const float* b_in  = (const float*)d_in[14];
    const float* W_out = (const float*)d_in[15];
    const float* b_out = (const float*)d_in[16];
    float* out = (float*)d_out;

    char* ws = (char*)d_ws;
    float*          MF   = (float*)(ws + 0);
    float*          DINV = (float*)(ws + 102400);
    int*            CNT  = (int*)(ws + 204800);
    unsigned short* IDX  = (unsigned short*)(ws + 307200);       // 26,214,400 B
    float*          XW   = (float*)(ws + 26521600);              // 13,107,200 B
    float*          H1   = (float*)(ws + 39628800);              // 13,107,200 B
    float*          EMB  = (float*)(ws + 52736000);              // 13,107,200 B

    hipMemsetAsync(CNT, 0, TT * NN * sizeof(int), stream);
    mf_kernel<<<dim3(100), dim3(256), 0, stream>>>(ego, MF);
    edge_kernel<<<dim3(TT * 16), dim3(256), 0, stream>>>(adj, MF, CNT, IDX);
    dinv_kernel<<<dim3(100), dim3(256), 0, stream>>>(MF, CNT, DINV);
    xw1_kernel<<<dim3(12800), dim3(256), 0, stream>>>(x, W1, DINV, XW);
    agg_kernel<<<dim3(TT * NN), dim3(128), 0, stream>>>(XW, MF, DINV, CNT, IDX, b1, H1, 1);
    xw2_kernel<<<dim3(TT * 16), dim3(128), 0, stream>>>(H1, W2, DINV, XW);
    agg_kernel<<<dim3(TT * NN), dim3(128), 0, stream>>>(XW, MF, DINV, CNT, IDX, b2, EMB, 0);
    node_attn_kernel<<<dim3(NN), dim3(256), 0, stream>>>(EMB, Wq, bq, Wk, bk, Wv, bv,
                                                         W_in, b_in, W_out, b_out, out);
}